// Round 1
// baseline (600.724 us; speedup 1.0000x reference)
//
#include <hip/hip_runtime.h>

#define N_NODES 50000
#define N_EDGES 640000
#define HD 128

// ---------------------------------------------------------------------------
// Shared-memory tiled [16 nodes] x [128] @ [128x128] GEMM phase.
// S: source tile [16][132] (padded rows: 132*4B = 528B, 16B-aligned, +4 bank shift)
// W staged in two 64-row halves (32KB LDS) to keep 3 blocks/CU resident.
// Thread (ln = tid>>4, jg = tid&15) accumulates 8 consecutive j outputs.
// ---------------------------------------------------------------------------
__device__ __forceinline__ void gemm_phase(const float (*S)[132], float* Ws,
                                           const float* __restrict__ W,
                                           int ln, int jg, int tid, float c[8]) {
  for (int half = 0; half < 2; ++half) {
    __syncthreads();
    const float4* wg = (const float4*)(W + half * 64 * HD);
    float4* wl = (float4*)Ws;
#pragma unroll
    for (int i = 0; i < 8; ++i) wl[tid + i * 256] = wg[tid + i * 256];
    __syncthreads();
    const float* srow = &S[ln][half * 64];
#pragma unroll
    for (int d = 0; d < 64; d += 4) {
      float4 xv = *(const float4*)(srow + d);
#pragma unroll
      for (int i = 0; i < 4; ++i) {
        float xval = (i == 0) ? xv.x : (i == 1) ? xv.y : (i == 2) ? xv.z : xv.w;
        float4 w0 = *(const float4*)&Ws[(d + i) * HD + jg * 8];
        float4 w1 = *(const float4*)&Ws[(d + i) * HD + jg * 8 + 4];
        c[0] = fmaf(xval, w0.x, c[0]);
        c[1] = fmaf(xval, w0.y, c[1]);
        c[2] = fmaf(xval, w0.z, c[2]);
        c[3] = fmaf(xval, w0.w, c[3]);
        c[4] = fmaf(xval, w1.x, c[4]);
        c[5] = fmaf(xval, w1.y, c[5]);
        c[6] = fmaf(xval, w1.z, c[6]);
        c[7] = fmaf(xval, w1.w, c[7]);
      }
    }
  }
}

// h0 = x@Wp + bp ; a = h0@Wm[:H] ; b = h0@Wm[H:] + bm   (bm folded into b)
__global__ __launch_bounds__(256, 3) void k_proj(
    const float* __restrict__ x, const float* __restrict__ Wp,
    const float* __restrict__ bp, const float* __restrict__ Wm,
    const float* __restrict__ bm, float* __restrict__ h0,
    float* __restrict__ a, float* __restrict__ b) {
  __shared__ float xs[16][132];
  __shared__ float h0s[16][132];
  __shared__ float Ws[64 * HD];
  const int tid = threadIdx.x;
  const int ln = tid >> 4, jg = tid & 15;
  const size_t node = (size_t)blockIdx.x * 16 + ln;

  {
    const float4* xg = (const float4*)(x + node * HD + jg * 8);
    *(float4*)&xs[ln][jg * 8] = xg[0];
    *(float4*)&xs[ln][jg * 8 + 4] = xg[1];
  }

  float c[8];
#pragma unroll
  for (int k = 0; k < 8; ++k) c[k] = bp[jg * 8 + k];
  gemm_phase(xs, Ws, Wp, ln, jg, tid, c);
  *(float4*)&h0s[ln][jg * 8] = make_float4(c[0], c[1], c[2], c[3]);
  *(float4*)&h0s[ln][jg * 8 + 4] = make_float4(c[4], c[5], c[6], c[7]);
  {
    float4* o = (float4*)(h0 + node * HD + jg * 8);
    o[0] = make_float4(c[0], c[1], c[2], c[3]);
    o[1] = make_float4(c[4], c[5], c[6], c[7]);
  }

#pragma unroll
  for (int k = 0; k < 8; ++k) c[k] = 0.f;
  gemm_phase(h0s, Ws, Wm, ln, jg, tid, c);
  {
    float4* o = (float4*)(a + node * HD + jg * 8);
    o[0] = make_float4(c[0], c[1], c[2], c[3]);
    o[1] = make_float4(c[4], c[5], c[6], c[7]);
  }

#pragma unroll
  for (int k = 0; k < 8; ++k) c[k] = bm[jg * 8 + k];
  gemm_phase(h0s, Ws, Wm + HD * HD, ln, jg, tid, c);
  {
    float4* o = (float4*)(b + node * HD + jg * 8);
    o[0] = make_float4(c[0], c[1], c[2], c[3]);
    o[1] = make_float4(c[4], c[5], c[6], c[7]);
  }
}

__global__ void k_hist(const int* __restrict__ dst, int* __restrict__ deg) {
  int e = blockIdx.x * 256 + threadIdx.x;
  if (e < N_EDGES) atomicAdd(&deg[dst[e]], 1);
}

#define SCAN_T 1024
__global__ __launch_bounds__(SCAN_T) void k_scan(const int* __restrict__ deg,
                                                 int* __restrict__ row_start,
                                                 int* __restrict__ cursor) {
  __shared__ int sums[SCAN_T];
  const int t = threadIdx.x;
  const int chunk = (N_NODES + SCAN_T - 1) / SCAN_T;  // 49
  int beg = t * chunk;
  int end = min(beg + chunk, N_NODES);
  int s = 0;
  for (int i = beg; i < end; ++i) s += deg[i];
  sums[t] = s;
  __syncthreads();
  for (int off = 1; off < SCAN_T; off <<= 1) {
    int v = (t >= off) ? sums[t - off] : 0;
    __syncthreads();
    if (t >= off) sums[t] += v;
    __syncthreads();
  }
  int run = (t == 0) ? 0 : sums[t - 1];
  for (int i = beg; i < end; ++i) {
    row_start[i] = run;
    cursor[i] = run;
    run += deg[i];
  }
  if (t == SCAN_T - 1) row_start[N_NODES] = run;  // == E
}

__global__ void k_scatter(const int* __restrict__ src, const int* __restrict__ dst,
                          int* __restrict__ cursor, int* __restrict__ es) {
  int e = blockIdx.x * 256 + threadIdx.x;
  if (e < N_EDGES) {
    int d = dst[e];
    int pos = atomicAdd(&cursor[d], 1);
    es[pos] = src[e];
  }
}

// pooled[n] = mean over incoming edges of relu(a[src] + b[n]) (bm already in b)
__global__ __launch_bounds__(256) void k_agg(const float* __restrict__ a,
                                             const float* __restrict__ b,
                                             const int* __restrict__ es,
                                             const int* __restrict__ row_start,
                                             float* __restrict__ pooled) {
  const int node = blockIdx.x * 4 + (threadIdx.x >> 6);
  const int lane = threadIdx.x & 63;
  const int s = row_start[node];
  const int e = row_start[node + 1];
  const float2 bv = ((const float2*)(b + (size_t)node * HD))[lane];
  float ax = 0.f, ay = 0.f;
  int i = s;
  for (; i + 4 <= e; i += 4) {
    int s0 = es[i], s1 = es[i + 1], s2 = es[i + 2], s3 = es[i + 3];
    float2 a0 = ((const float2*)(a + (size_t)s0 * HD))[lane];
    float2 a1 = ((const float2*)(a + (size_t)s1 * HD))[lane];
    float2 a2 = ((const float2*)(a + (size_t)s2 * HD))[lane];
    float2 a3 = ((const float2*)(a + (size_t)s3 * HD))[lane];
    ax += fmaxf(a0.x + bv.x, 0.f);
    ay += fmaxf(a0.y + bv.y, 0.f);
    ax += fmaxf(a1.x + bv.x, 0.f);
    ay += fmaxf(a1.y + bv.y, 0.f);
    ax += fmaxf(a2.x + bv.x, 0.f);
    ay += fmaxf(a2.y + bv.y, 0.f);
    ax += fmaxf(a3.x + bv.x, 0.f);
    ay += fmaxf(a3.y + bv.y, 0.f);
  }
  for (; i < e; ++i) {
    int s0 = es[i];
    float2 a0 = ((const float2*)(a + (size_t)s0 * HD))[lane];
    ax += fmaxf(a0.x + bv.x, 0.f);
    ay += fmaxf(a0.y + bv.y, 0.f);
  }
  const float inv = 1.f / fmaxf((float)(e - s), 1.f);
  ((float2*)(pooled + (size_t)node * HD))[lane] = make_float2(ax * inv, ay * inv);
}

// upd = h0@Wu[:H] + pooled@Wu[H:] + bu ; hn = relu(h0+upd) ; LayerNorm ; graph-sum
__global__ __launch_bounds__(256, 3) void k_upd(
    const float* __restrict__ h0, const float* __restrict__ pooled,
    const float* __restrict__ Wu, const float* __restrict__ bu,
    const float* __restrict__ gamma, const float* __restrict__ beta,
    float* __restrict__ gsum) {
  __shared__ float hs[16][132];
  __shared__ float ps[16][132];
  __shared__ float Ws[64 * HD];
  const int tid = threadIdx.x;
  const int ln = tid >> 4, jg = tid & 15;
  const size_t node = (size_t)blockIdx.x * 16 + ln;

  {
    const float4* hg = (const float4*)(h0 + node * HD + jg * 8);
    *(float4*)&hs[ln][jg * 8] = hg[0];
    *(float4*)&hs[ln][jg * 8 + 4] = hg[1];
    const float4* pg = (const float4*)(pooled + node * HD + jg * 8);
    *(float4*)&ps[ln][jg * 8] = pg[0];
    *(float4*)&ps[ln][jg * 8 + 4] = pg[1];
  }

  float c[8];
#pragma unroll
  for (int k = 0; k < 8; ++k) c[k] = bu[jg * 8 + k];
  gemm_phase(hs, Ws, Wu, ln, jg, tid, c);
  gemm_phase(ps, Ws, Wu + HD * HD, ln, jg, tid, c);

  float hv[8];
  float sum = 0.f, sq = 0.f;
#pragma unroll
  for (int k = 0; k < 8; ++k) {
    float v = hs[ln][jg * 8 + k] + c[k];
    v = fmaxf(v, 0.f);
    hv[k] = v;
    sum += v;
    sq += v * v;
  }
#pragma unroll
  for (int m = 1; m < 16; m <<= 1) {
    sum += __shfl_xor(sum, m);
    sq += __shfl_xor(sq, m);
  }
  const float mu = sum * (1.f / 128.f);
  const float var = sq * (1.f / 128.f) - mu * mu;
  const float rs = rsqrtf(var + 1e-6f);

  __syncthreads();  // everyone done reading ps in gemm_phase
#pragma unroll
  for (int k = 0; k < 8; ++k) {
    int j = jg * 8 + k;
    ps[ln][j] = (hv[k] - mu) * rs * gamma[j] + beta[j];
  }
  __syncthreads();
  if (tid < HD) {
    float s = 0.f;
#pragma unroll
    for (int l = 0; l < 16; ++l) s += ps[l][tid];
    atomicAdd(&gsum[tid], s);
  }
}

__global__ void k_final(const float* __restrict__ gsum, const float* __restrict__ Wd,
                        const float* __restrict__ bd, float* __restrict__ out) {
  int o = threadIdx.x;
  if (o < 32) {
    float acc = bd[o];
    const float invN = 1.f / (float)N_NODES;
    for (int d = 0; d < HD; ++d) acc = fmaf(gsum[d] * invN, Wd[d * 32 + o], acc);
    out[o] = acc;
  }
}

extern "C" void kernel_launch(void* const* d_in, const int* in_sizes, int n_in,
                              void* d_out, int out_size, void* d_ws, size_t ws_size,
                              hipStream_t stream) {
  (void)in_sizes; (void)n_in; (void)out_size; (void)ws_size;
  const float* x    = (const float*)d_in[0];
  const int* esrc   = (const int*)d_in[1];
  const int* edst   = (const int*)d_in[2];
  const float* Wp   = (const float*)d_in[3];
  const float* bp   = (const float*)d_in[4];
  const float* Wm   = (const float*)d_in[5];
  const float* bm   = (const float*)d_in[6];
  const float* Wu   = (const float*)d_in[7];
  const float* bu   = (const float*)d_in[8];
  const float* gam  = (const float*)d_in[9];
  const float* bet  = (const float*)d_in[10];
  const float* Wd   = (const float*)d_in[11];
  const float* bd   = (const float*)d_in[12];
  float* out = (float*)d_out;

  char* ws = (char*)d_ws;
  size_t off = 0;
  float* h0     = (float*)(ws + off); off += (size_t)N_NODES * HD * 4;
  float* a      = (float*)(ws + off); off += (size_t)N_NODES * HD * 4;
  float* b      = (float*)(ws + off); off += (size_t)N_NODES * HD * 4;
  float* pooled = (float*)(ws + off); off += (size_t)N_NODES * HD * 4;
  int* es       = (int*)(ws + off);   off += (size_t)N_EDGES * 4;
  int* deg      = (int*)(ws + off);   off += (size_t)N_NODES * 4;   // zeroed
  float* gsum   = (float*)(ws + off); off += 128 * 4;               // zeroed (adjacent)
  int* row_start= (int*)(ws + off);   off += (size_t)(N_NODES + 1) * 4;
  int* cursor   = (int*)(ws + off);   off += (size_t)N_NODES * 4;

  hipMemsetAsync(deg, 0, (size_t)(N_NODES + 128) * 4, stream);
  k_proj<<<N_NODES / 16, 256, 0, stream>>>(x, Wp, bp, Wm, bm, h0, a, b);
  k_hist<<<(N_EDGES + 255) / 256, 256, 0, stream>>>(edst, deg);
  k_scan<<<1, SCAN_T, 0, stream>>>(deg, row_start, cursor);
  k_scatter<<<(N_EDGES + 255) / 256, 256, 0, stream>>>(esrc, edst, cursor, es);
  k_agg<<<N_NODES / 4, 256, 0, stream>>>(a, b, es, row_start, pooled);
  k_upd<<<N_NODES / 16, 256, 0, stream>>>(h0, pooled, Wu, bu, gam, bet, gsum);
  k_final<<<1, 64, 0, stream>>>(gsum, Wd, bd, out);
}

// Round 3
// 383.474 us; speedup vs baseline: 1.5665x; 1.5665x over previous
//
#include <hip/hip_runtime.h>

#define N_NODES 50000
#define N_EDGES 640000
#define HD 128
#define TILE_N 128
#define NSCB 196  // ceil(50000/256)

// ---------------------------------------------------------------------------
// Register-tiled fp32 GEMM building blocks.
// Block = 256 threads = (jg = tid&15) x (ng = tid>>4).
// Thread tile: 8 nodes (ng*8+i) x 8 cols {4jg..4jg+3, 64+4jg..64+4jg+3}.
// S tile [128 nodes][128 d] in LDS, float4 slot XOR-swizzled by (node>>3)&3
// so the 4 node-groups of a wave read 4 distinct float4s (16 banks, free).
// W tile [128 d][128 cols] linear; 16 consecutive float4s x 4-way broadcast
// = 2 words/bank = free. LDS bytes/FMA ~ 1.0 -> VALU-bound by design.
// ---------------------------------------------------------------------------

__device__ __forceinline__ void fma4(float4& a, float s, const float4& w) {
  a.x = fmaf(s, w.x, a.x);
  a.y = fmaf(s, w.y, a.y);
  a.z = fmaf(s, w.z, a.z);
  a.w = fmaf(s, w.w, a.w);
}

__device__ __forceinline__ void mm_tile(const float* Ssh, const float* Wsh,
                                        int jg, int ng, float4 acc0[8], float4 acc1[8]) {
  const float4* S4 = (const float4*)Ssh;
  const float4* W4 = (const float4*)Wsh;
  const int ngs = ng & 3;
#pragma unroll 2
  for (int t = 0; t < 32; ++t) {
    float4 w0[4], w1[4];
#pragma unroll
    for (int k = 0; k < 4; ++k) {
      w0[k] = W4[(4 * t + k) * 32 + jg];
      w1[k] = W4[(4 * t + k) * 32 + 16 + jg];
    }
#pragma unroll
    for (int i = 0; i < 8; ++i) {
      float4 sv = S4[(ng * 8 + i) * 32 + (t ^ ngs)];
      fma4(acc0[i], sv.x, w0[0]);
      fma4(acc1[i], sv.x, w1[0]);
      fma4(acc0[i], sv.y, w0[1]);
      fma4(acc1[i], sv.y, w1[1]);
      fma4(acc0[i], sv.z, w0[2]);
      fma4(acc1[i], sv.z, w1[2]);
      fma4(acc0[i], sv.w, w0[3]);
      fma4(acc1[i], sv.w, w1[3]);
    }
  }
}

// Stage 128 rows of src[N][128] into swizzled S tile; zero-fill past N.
// 128 nodes x 32 float4 = 4096 float4 = 16 per thread.
__device__ __forceinline__ void stage_S(const float* __restrict__ src, float* Ssh,
                                        int bnode0, int tid) {
  const float4* g = (const float4*)src;
  float4* l = (float4*)Ssh;
#pragma unroll
  for (int c = 0; c < 16; ++c) {
    int f4 = c * 256 + tid;
    int nl = f4 >> 5;
    int t = f4 & 31;
    int gn = bnode0 + nl;
    float4 v = make_float4(0.f, 0.f, 0.f, 0.f);
    if (gn < N_NODES) v = g[(size_t)gn * 32 + t];
    int sw = (nl >> 3) & 3;
    l[(f4 & ~31) | (t ^ sw)] = v;
  }
}

// 128x128 floats = 4096 float4 = 16 per thread.
__device__ __forceinline__ void stage_W(const float* __restrict__ src, float* Wsh, int tid) {
  const float4* g = (const float4*)src;
  float4* l = (float4*)Wsh;
#pragma unroll
  for (int c = 0; c < 16; ++c) {
    int f4 = c * 256 + tid;
    l[f4] = g[f4];
  }
}

// Write thread tile into swizzled S (for chained GEMMs).
__device__ __forceinline__ void store_tile_S(float* Ssh, int jg, int ng,
                                             const float4 a0[8], const float4 a1[8]) {
  float4* l = (float4*)Ssh;
  const int ngs = ng & 3;
#pragma unroll
  for (int i = 0; i < 8; ++i) {
    int n = ng * 8 + i;
    l[n * 32 + (jg ^ ngs)] = a0[i];
    l[n * 32 + ((16 + jg) ^ ngs)] = a1[i];
  }
}

__device__ __forceinline__ void store_tile_G(float* __restrict__ dst, int bnode0, int jg,
                                             int ng, const float4 a0[8], const float4 a1[8]) {
  float4* g = (float4*)dst;
#pragma unroll
  for (int i = 0; i < 8; ++i) {
    int gn = bnode0 + ng * 8 + i;
    if (gn < N_NODES) {
      g[(size_t)gn * 32 + jg] = a0[i];
      g[(size_t)gn * 32 + 16 + jg] = a1[i];
    }
  }
}

// h0 = x@Wp + bp ; a = h0@Wm[:H] ; b = h0@Wm[H:] + bm
__global__ __launch_bounds__(256, 1) void k_proj(
    const float* __restrict__ x, const float* __restrict__ Wp,
    const float* __restrict__ bp, const float* __restrict__ Wm,
    const float* __restrict__ bm, float* __restrict__ h0,
    float* __restrict__ a, float* __restrict__ b) {
  __shared__ float Ssh[TILE_N * HD];
  __shared__ float Wsh[HD * HD];
  const int tid = threadIdx.x;
  const int jg = tid & 15, ng = tid >> 4;
  const int bnode0 = blockIdx.x * TILE_N;

  stage_S(x, Ssh, bnode0, tid);
  stage_W(Wp, Wsh, tid);
  __syncthreads();

  float4 a0[8], a1[8];
  {
    float4 v0 = ((const float4*)bp)[jg], v1 = ((const float4*)bp)[16 + jg];
#pragma unroll
    for (int i = 0; i < 8; ++i) { a0[i] = v0; a1[i] = v1; }
  }
  mm_tile(Ssh, Wsh, jg, ng, a0, a1);  // h0
  __syncthreads();
  store_tile_S(Ssh, jg, ng, a0, a1);
  stage_W(Wm, Wsh, tid);
  store_tile_G(h0, bnode0, jg, ng, a0, a1);
  __syncthreads();

#pragma unroll
  for (int i = 0; i < 8; ++i) {
    a0[i] = make_float4(0.f, 0.f, 0.f, 0.f);
    a1[i] = make_float4(0.f, 0.f, 0.f, 0.f);
  }
  mm_tile(Ssh, Wsh, jg, ng, a0, a1);  // a = h0@Wm[:H]
  store_tile_G(a, bnode0, jg, ng, a0, a1);
  __syncthreads();
  stage_W(Wm + HD * HD, Wsh, tid);
  __syncthreads();

  {
    float4 v0 = ((const float4*)bm)[jg], v1 = ((const float4*)bm)[16 + jg];
#pragma unroll
    for (int i = 0; i < 8; ++i) { a0[i] = v0; a1[i] = v1; }
  }
  mm_tile(Ssh, Wsh, jg, ng, a0, a1);  // b = h0@Wm[H:] + bm
  store_tile_G(b, bnode0, jg, ng, a0, a1);
}

__global__ void k_hist(const int* __restrict__ dst, int* __restrict__ deg) {
  int e = blockIdx.x * 256 + threadIdx.x;
  if (e < N_EDGES) atomicAdd(&deg[dst[e]], 1);
}

__global__ __launch_bounds__(256) void k_scan1(const int* __restrict__ deg,
                                               int* __restrict__ bsum) {
  __shared__ int sh[256];
  int i = blockIdx.x * 256 + threadIdx.x;
  sh[threadIdx.x] = (i < N_NODES) ? deg[i] : 0;
  __syncthreads();
  for (int off = 128; off > 0; off >>= 1) {
    if (threadIdx.x < off) sh[threadIdx.x] += sh[threadIdx.x + off];
    __syncthreads();
  }
  if (threadIdx.x == 0) bsum[blockIdx.x] = sh[0];
}

__global__ __launch_bounds__(256) void k_scan2(const int* __restrict__ bsum,
                                               int* __restrict__ boff,
                                               int* __restrict__ row_start) {
  __shared__ int sh[256];
  int t = threadIdx.x;
  int v = (t < NSCB) ? bsum[t] : 0;
  sh[t] = v;
  __syncthreads();
  for (int off = 1; off < 256; off <<= 1) {
    int add = (t >= off) ? sh[t - off] : 0;
    __syncthreads();
    sh[t] += add;
    __syncthreads();
  }
  if (t < NSCB) boff[t] = sh[t] - v;  // exclusive
  if (t == 255) row_start[N_NODES] = sh[255];
}

__global__ __launch_bounds__(256) void k_scan3(const int* __restrict__ deg,
                                               const int* __restrict__ boff,
                                               int* __restrict__ row_start,
                                               int* __restrict__ cursor) {
  __shared__ int sh[256];
  int t = threadIdx.x;
  int i = blockIdx.x * 256 + t;
  int v = (i < N_NODES) ? deg[i] : 0;
  sh[t] = v;
  __syncthreads();
  for (int off = 1; off < 256; off <<= 1) {
    int add = (t >= off) ? sh[t - off] : 0;
    __syncthreads();
    sh[t] += add;
    __syncthreads();
  }
  if (i < N_NODES) {
    int ex = boff[blockIdx.x] + sh[t] - v;
    row_start[i] = ex;
    cursor[i] = ex;
  }
}

__global__ void k_scatter(const int* __restrict__ src, const int* __restrict__ dst,
                          int* __restrict__ cursor, int* __restrict__ es) {
  int e = blockIdx.x * 256 + threadIdx.x;
  if (e < N_EDGES) {
    int d = dst[e];
    int pos = atomicAdd(&cursor[d], 1);
    es[pos] = src[e];
  }
}

// pooled[n] = mean over incoming edges of relu(a[src] + b[n]) (bm already in b)
__global__ __launch_bounds__(256) void k_agg(const float* __restrict__ a,
                                             const float* __restrict__ b,
                                             const int* __restrict__ es,
                                             const int* __restrict__ row_start,
                                             float* __restrict__ pooled) {
  const int node = blockIdx.x * 4 + (threadIdx.x >> 6);
  const int lane = threadIdx.x & 63;
  const int s = row_start[node];
  const int e = row_start[node + 1];
  const float2 bv = ((const float2*)(b + (size_t)node * HD))[lane];
  float ax = 0.f, ay = 0.f;
  int i = s;
  for (; i + 4 <= e; i += 4) {
    int s0 = es[i], s1 = es[i + 1], s2 = es[i + 2], s3 = es[i + 3];
    float2 a0 = ((const float2*)(a + (size_t)s0 * HD))[lane];
    float2 a1 = ((const float2*)(a + (size_t)s1 * HD))[lane];
    float2 a2 = ((const float2*)(a + (size_t)s2 * HD))[lane];
    float2 a3 = ((const float2*)(a + (size_t)s3 * HD))[lane];
    ax += fmaxf(a0.x + bv.x, 0.f);
    ay += fmaxf(a0.y + bv.y, 0.f);
    ax += fmaxf(a1.x + bv.x, 0.f);
    ay += fmaxf(a1.y + bv.y, 0.f);
    ax += fmaxf(a2.x + bv.x, 0.f);
    ay += fmaxf(a2.y + bv.y, 0.f);
    ax += fmaxf(a3.x + bv.x, 0.f);
    ay += fmaxf(a3.y + bv.y, 0.f);
  }
  for (; i < e; ++i) {
    int s0 = es[i];
    float2 a0 = ((const float2*)(a + (size_t)s0 * HD))[lane];
    ax += fmaxf(a0.x + bv.x, 0.f);
    ay += fmaxf(a0.y + bv.y, 0.f);
  }
  const float inv = 1.f / fmaxf((float)(e - s), 1.f);
  ((float2*)(pooled + (size_t)node * HD))[lane] = make_float2(ax * inv, ay * inv);
}

// upd = h0@Wu[:H] + pooled@Wu[H:] + bu ; hn = relu(h0+upd) ; LN ; graph-sum
__global__ __launch_bounds__(256, 1) void k_upd(
    const float* __restrict__ h0, const float* __restrict__ pooled,
    const float* __restrict__ Wu, const float* __restrict__ bu,
    const float* __restrict__ gamma, const float* __restrict__ beta,
    float* __restrict__ gsum) {
  __shared__ float Ssh[TILE_N * HD];
  __shared__ float Wsh[HD * HD];
  const int tid = threadIdx.x;
  const int jg = tid & 15, ng = tid >> 4;
  const int ngs = ng & 3;
  const int bnode0 = blockIdx.x * TILE_N;

  stage_S(pooled, Ssh, bnode0, tid);
  stage_W(Wu + HD * HD, Wsh, tid);  // Wu[H:]
  __syncthreads();

  float4 a0[8], a1[8];
  {
    float4 v0 = ((const float4*)bu)[jg], v1 = ((const float4*)bu)[16 + jg];
#pragma unroll
    for (int i = 0; i < 8; ++i) { a0[i] = v0; a1[i] = v1; }
  }
  mm_tile(Ssh, Wsh, jg, ng, a0, a1);  // pooled@Wu[H:] + bu
  __syncthreads();
  stage_S(h0, Ssh, bnode0, tid);
  stage_W(Wu, Wsh, tid);  // Wu[:H]
  __syncthreads();
  mm_tile(Ssh, Wsh, jg, ng, a0, a1);  // += h0@Wu[:H]

  // residual + relu + LayerNorm + masked graph partial
  float4 gam0 = ((const float4*)gamma)[jg], gam1 = ((const float4*)gamma)[16 + jg];
  float4 bet0 = ((const float4*)beta)[jg], bet1 = ((const float4*)beta)[16 + jg];
  float4 gpa = make_float4(0.f, 0.f, 0.f, 0.f);
  float4 gpb = make_float4(0.f, 0.f, 0.f, 0.f);
  const float4* S4 = (const float4*)Ssh;
#pragma unroll
  for (int i = 0; i < 8; ++i) {
    int n = ng * 8 + i;
    float4 h0v0 = S4[n * 32 + (jg ^ ngs)];
    float4 h0v1 = S4[n * 32 + ((16 + jg) ^ ngs)];
    float4 v0, v1;
    v0.x = fmaxf(h0v0.x + a0[i].x, 0.f);
    v0.y = fmaxf(h0v0.y + a0[i].y, 0.f);
    v0.z = fmaxf(h0v0.z + a0[i].z, 0.f);
    v0.w = fmaxf(h0v0.w + a0[i].w, 0.f);
    v1.x = fmaxf(h0v1.x + a1[i].x, 0.f);
    v1.y = fmaxf(h0v1.y + a1[i].y, 0.f);
    v1.z = fmaxf(h0v1.z + a1[i].z, 0.f);
    v1.w = fmaxf(h0v1.w + a1[i].w, 0.f);
    float sum = v0.x + v0.y + v0.z + v0.w + v1.x + v1.y + v1.z + v1.w;
    float sq = v0.x * v0.x + v0.y * v0.y + v0.z * v0.z + v0.w * v0.w +
               v1.x * v1.x + v1.y * v1.y + v1.z * v1.z + v1.w * v1.w;
#pragma unroll
    for (int m = 1; m < 16; m <<= 1) {
      sum += __shfl_xor(sum, m);
      sq += __shfl_xor(sq, m);
    }
    float mu = sum * (1.f / 128.f);
    float var = sq * (1.f / 128.f) - mu * mu;
    float rs = rsqrtf(var + 1e-6f);
    if (bnode0 + n < N_NODES) {
      gpa.x += (v0.x - mu) * rs * gam0.x + bet0.x;
      gpa.y += (v0.y - mu) * rs * gam0.y + bet0.y;
      gpa.z += (v0.z - mu) * rs * gam0.z + bet0.z;
      gpa.w += (v0.w - mu) * rs * gam0.w + bet0.w;
      gpb.x += (v1.x - mu) * rs * gam1.x + bet1.x;
      gpb.y += (v1.y - mu) * rs * gam1.y + bet1.y;
      gpb.z += (v1.z - mu) * rs * gam1.z + bet1.z;
      gpb.w += (v1.w - mu) * rs * gam1.w + bet1.w;
    }
  }
  // reduce across the 4 node-groups of the wave (lane bits 4,5)
#pragma unroll
  for (int m = 16; m < 64; m <<= 1) {
    gpa.x += __shfl_xor(gpa.x, m);
    gpa.y += __shfl_xor(gpa.y, m);
    gpa.z += __shfl_xor(gpa.z, m);
    gpa.w += __shfl_xor(gpa.w, m);
    gpb.x += __shfl_xor(gpb.x, m);
    gpb.y += __shfl_xor(gpb.y, m);
    gpb.z += __shfl_xor(gpb.z, m);
    gpb.w += __shfl_xor(gpb.w, m);
  }
  __syncthreads();  // Wsh reads done; reuse as scratch
  float* gs = Wsh;  // [4 waves][128]
  int w = tid >> 6;
  if ((tid & 63) < 16) {
    ((float4*)gs)[w * 32 + jg] = gpa;
    ((float4*)gs)[w * 32 + 16 + jg] = gpb;
  }
  __syncthreads();
  if (tid < HD) {
    float s = gs[tid] + gs[128 + tid] + gs[256 + tid] + gs[384 + tid];
    atomicAdd(&gsum[tid], s);
  }
}

__global__ void k_final(const float* __restrict__ gsum, const float* __restrict__ Wd,
                        const float* __restrict__ bd, float* __restrict__ out) {
  int o = threadIdx.x;
  if (o < 32) {
    float acc = bd[o];
    const float invN = 1.f / (float)N_NODES;
    for (int d = 0; d < HD; ++d) acc = fmaf(gsum[d] * invN, Wd[d * 32 + o], acc);
    out[o] = acc;
  }
}

extern "C" void kernel_launch(void* const* d_in, const int* in_sizes, int n_in,
                              void* d_out, int out_size, void* d_ws, size_t ws_size,
                              hipStream_t stream) {
  (void)in_sizes; (void)n_in; (void)out_size; (void)ws_size;
  const float* x    = (const float*)d_in[0];
  const int* esrc   = (const int*)d_in[1];
  const int* edst   = (const int*)d_in[2];
  const float* Wp   = (const float*)d_in[3];
  const float* bp   = (const float*)d_in[4];
  const float* Wm   = (const float*)d_in[5];
  const float* bm   = (const float*)d_in[6];
  const float* Wu   = (const float*)d_in[7];
  const float* bu   = (const float*)d_in[8];
  const float* gam  = (const float*)d_in[9];
  const float* bet  = (const float*)d_in[10];
  const float* Wd   = (const float*)d_in[11];
  const float* bd   = (const float*)d_in[12];
  float* out = (float*)d_out;

  char* ws = (char*)d_ws;
  size_t off = 0;
  float* h0     = (float*)(ws + off); off += (size_t)N_NODES * HD * 4;
  float* a      = (float*)(ws + off); off += (size_t)N_NODES * HD * 4;
  float* b      = (float*)(ws + off); off += (size_t)N_NODES * HD * 4;
  float* pooled = (float*)(ws + off); off += (size_t)N_NODES * HD * 4;
  int* es       = (int*)(ws + off);   off += (size_t)N_EDGES * 4;
  int* deg      = (int*)(ws + off);   off += (size_t)N_NODES * 4;   // zeroed
  float* gsum   = (float*)(ws + off); off += 128 * 4;               // zeroed (adjacent)
  int* row_start= (int*)(ws + off);   off += (size_t)(N_NODES + 1) * 4;
  int* cursor   = (int*)(ws + off);   off += (size_t)N_NODES * 4;
  int* bsum     = (int*)(ws + off);   off += (size_t)NSCB * 4;
  int* boff     = (int*)(ws + off);   off += (size_t)NSCB * 4;

  hipMemsetAsync(deg, 0, (size_t)(N_NODES + 128) * 4, stream);
  k_proj<<<(N_NODES + TILE_N - 1) / TILE_N, 256, 0, stream>>>(x, Wp, bp, Wm, bm, h0, a, b);
  k_hist<<<(N_EDGES + 255) / 256, 256, 0, stream>>>(edst, deg);
  k_scan1<<<NSCB, 256, 0, stream>>>(deg, bsum);
  k_scan2<<<1, 256, 0, stream>>>(bsum, boff, row_start);
  k_scan3<<<NSCB, 256, 0, stream>>>(deg, boff, row_start, cursor);
  k_scatter<<<(N_EDGES + 255) / 256, 256, 0, stream>>>(esrc, edst, cursor, es);
  k_agg<<<(N_NODES + 3) / 4, 256, 0, stream>>>(a, b, es, row_start, pooled);
  k_upd<<<(N_NODES + TILE_N - 1) / TILE_N, 256, 0, stream>>>(h0, pooled, Wu, bu, gam, bet, gsum);
  k_final<<<1, 64, 0, stream>>>(gsum, Wd, bd, out);
}